// Round 3
// baseline (160.980 us; speedup 1.0000x reference)
//
#include <hip/hip_runtime.h>

// Concordance index, full-matrix symmetric formulation:
//   answer = (CC_full - K) / (TP_full - K),  K = #(status==1)
// Distinct-value assumption: le == !ge (ties are measure-zero for normal
// floats; threshold is 1e-2).
// Per (i,j) with le=!ge:
//   cc = (ge&geh&stj) | (!ge&!geh&sti)
//   tp = (!ge&sti) | (ge&stj)
// j-tile is PARTITIONED BY STATUS in LDS (st=1 first, NaN-padded to x4),
// so the inner loops have no status logic at all:
//   st1 loop: geCnt1+=ge, ccA+=ge&geh, orCnt1+=ge|geh
//   st0 loop: geCnt0+=ge, orCnt0+=ge|geh
// then per lane: tp = geCnt1 + sti*((J1-geCnt1)+(J0-geCnt0))
//               cc = ccA    + sti*((J1-orCnt1)+(J0-orCnt0))
// NaN entries (i-pads, j-pads, partition padding) compare false -> they add
// 0 to every counter and are excluded from J1/J0, so they cancel exactly.

#define BLOCK 256
#define IT 2
#define ICHUNK (BLOCK * IT)   // 512
#define JCHUNK 256
#define JPAD 8                // room for rounding both regions up to x4

__global__ __launch_bounds__(BLOCK) void cindex_kernel(
    const float* __restrict__ y, const float* __restrict__ yh,
    const int* __restrict__ status, int n, int nblocks,
    unsigned long long* __restrict__ acc,   // [0]=cc,[1]=tp, then u32 done ctr
    float* __restrict__ out)
{
    __shared__ __align__(16) float s_y[JCHUNK + JPAD];
    __shared__ __align__(16) float s_yh[JCHUNK + JPAD];
    __shared__ int s_cnt1[BLOCK / 64];
    __shared__ int s_last;
    __shared__ unsigned s_rc[BLOCK / 64], s_rt[BLOCK / 64];

    const int tid = threadIdx.x;
    const int wav = tid >> 6, lane = tid & 63;
    const int ibase = blockIdx.x * ICHUNK;
    const int jbase = blockIdx.y * JCHUNK;
    const float NANF = __int_as_float(0x7fc00000);

    // ---- stage j tile, partitioned by status ----
    for (int t = tid; t < JCHUNK + JPAD; t += BLOCK) { s_y[t] = NANF; s_yh[t] = NANF; }
    int j = jbase + tid;
    bool jinb = j < n;
    float yv  = jinb ? y[j]  : NANF;
    float yhv = jinb ? yh[j] : NANF;
    bool stj  = jinb && (status[j] == 1);
    unsigned long long m = __ballot(stj);
    if (lane == 0) s_cnt1[wav] = __popcll(m);
    __syncthreads();

    int J1 = s_cnt1[0] + s_cnt1[1] + s_cnt1[2] + s_cnt1[3];
    int J1p = (J1 + 3) & ~3;
    int pre1 = 0, pre0 = 0;
    for (int w = 0; w < wav; ++w) { pre1 += s_cnt1[w]; pre0 += 64 - s_cnt1[w]; }
    unsigned long long below = m & ((1ull << lane) - 1ull);
    int nbelow1 = __popcll(below);
    int slot = stj ? (pre1 + nbelow1)
                   : (J1p + pre0 + (lane - nbelow1));
    s_y[slot] = yv; s_yh[slot] = yhv;
    __syncthreads();

    int J0all = JCHUNK - J1;              // includes j-pads (they're NaN)
    int J0p = (J0all + 3) & ~3;

    // ---- i fragment ----
    float yi[IT], yhi[IT];
    unsigned sti[IT];
#pragma unroll
    for (int k = 0; k < IT; ++k) {
        int i = ibase + k * BLOCK + tid;
        bool inb = i < n;
        yi[k]  = inb ? y[i]  : NANF;
        yhi[k] = inb ? yh[i] : NANF;
        sti[k] = (inb && (status[i] == 1)) ? 1u : 0u;
    }

    unsigned g1[IT], ca[IT], o1[IT], g0[IT], o0[IT];
#pragma unroll
    for (int k = 0; k < IT; ++k) { g1[k] = 0; ca[k] = 0; o1[k] = 0; g0[k] = 0; o0[k] = 0; }

    // ---- st=1 j's: 3 accumulators ----
    for (int b = 0; b < J1p; b += 4) {
        float4 py = *(const float4*)(s_y  + b);
        float4 ph = *(const float4*)(s_yh + b);
#pragma unroll
        for (int k = 0; k < IT; ++k) {
            bool ge, gh;
            ge = yi[k] >= py.x; gh = yhi[k] >= ph.x;
            g1[k] += ge; ca[k] += (ge & gh); o1[k] += (ge | gh);
            ge = yi[k] >= py.y; gh = yhi[k] >= ph.y;
            g1[k] += ge; ca[k] += (ge & gh); o1[k] += (ge | gh);
            ge = yi[k] >= py.z; gh = yhi[k] >= ph.z;
            g1[k] += ge; ca[k] += (ge & gh); o1[k] += (ge | gh);
            ge = yi[k] >= py.w; gh = yhi[k] >= ph.w;
            g1[k] += ge; ca[k] += (ge & gh); o1[k] += (ge | gh);
        }
    }
    // ---- st=0 j's: 2 accumulators ----
    for (int b = J1p; b < J1p + J0p; b += 4) {
        float4 py = *(const float4*)(s_y  + b);
        float4 ph = *(const float4*)(s_yh + b);
#pragma unroll
        for (int k = 0; k < IT; ++k) {
            bool ge, gh;
            ge = yi[k] >= py.x; gh = yhi[k] >= ph.x;
            g0[k] += ge; o0[k] += (ge | gh);
            ge = yi[k] >= py.y; gh = yhi[k] >= ph.y;
            g0[k] += ge; o0[k] += (ge | gh);
            ge = yi[k] >= py.z; gh = yhi[k] >= ph.z;
            g0[k] += ge; o0[k] += (ge | gh);
            ge = yi[k] >= py.w; gh = yhi[k] >= ph.w;
            g0[k] += ge; o0[k] += (ge | gh);
        }
    }

    // ---- per-lane combine (sti applied once) ----
    int Jreal = n - jbase; if (Jreal > JCHUNK) Jreal = JCHUNK; if (Jreal < 0) Jreal = 0;
    unsigned J0real = (unsigned)(Jreal - J1);
    unsigned cc = 0, tp = 0;
#pragma unroll
    for (int k = 0; k < IT; ++k) {
        tp += g1[k] + (sti[k] ? ((unsigned)J1 - g1[k]) + (J0real - g0[k]) : 0u);
        cc += ca[k] + (sti[k] ? ((unsigned)J1 - o1[k]) + (J0real - o0[k]) : 0u);
    }

    // ---- block reduce ----
#pragma unroll
    for (int off = 32; off > 0; off >>= 1) {
        cc += __shfl_down(cc, off, 64);
        tp += __shfl_down(tp, off, 64);
    }
    if (lane == 0) { s_rc[wav] = cc; s_rt[wav] = tp; }
    __syncthreads();

    unsigned* done = (unsigned*)(acc + 2);
    if (tid == 0) {
        unsigned c = s_rc[0] + s_rc[1] + s_rc[2] + s_rc[3];
        unsigned t = s_rt[0] + s_rt[1] + s_rt[2] + s_rt[3];
        atomicAdd(&acc[0], (unsigned long long)c);
        atomicAdd(&acc[1], (unsigned long long)t);
        __threadfence();
        unsigned prev = atomicAdd(done, 1u);
        s_last = (prev == (unsigned)(nblocks - 1));
    }
    __syncthreads();

    // ---- last block: fused finalize ----
    if (s_last) {
        __threadfence();
        int k = 0;
        for (int i = tid; i < n; i += BLOCK) k += (status[i] == 1);
#pragma unroll
        for (int off = 32; off > 0; off >>= 1) k += __shfl_down(k, off, 64);
        __shared__ int s_k[BLOCK / 64];
        if (lane == 0) s_k[wav] = k;
        __syncthreads();
        if (tid == 0) {
            int K = s_k[0] + s_k[1] + s_k[2] + s_k[3];
            unsigned long long C = atomicAdd(&acc[0], 0ull);
            unsigned long long T = atomicAdd(&acc[1], 0ull);
            long long cn = (long long)C - K;
            long long tn = (long long)T - K;
            out[0] = (float)cn / (float)tn;
        }
    }
}

extern "C" void kernel_launch(void* const* d_in, const int* in_sizes, int n_in,
                              void* d_out, int out_size, void* d_ws, size_t ws_size,
                              hipStream_t stream) {
    const float* y      = (const float*)d_in[0];
    const float* y_hat  = (const float*)d_in[1];
    const int*   status = (const int*)d_in[2];
    float* out = (float*)d_out;
    int n = in_sizes[0];

    unsigned long long* acc = (unsigned long long*)d_ws;
    hipMemsetAsync(acc, 0, 24, stream);   // cc, tp, done-counter

    int gi = (n + ICHUNK - 1) / ICHUNK;   // 32 for n=16384
    int gj = (n + JCHUNK - 1) / JCHUNK;   // 64 -> 2048 blocks
    hipLaunchKernelGGL(cindex_kernel, dim3(gi, gj), dim3(BLOCK), 0, stream,
                       y, y_hat, status, n, gi * gj, acc, out);
}

// Round 4
// 94.938 us; speedup vs baseline: 1.6956x; 1.6956x over previous
//
#include <hip/hip_runtime.h>

// Concordance index, status-partitioned formulation.
// Full-matrix symmetric counts (answer = (CC_full-K)/(TP_full-K), K=#st1),
// with le == !ge (distinct values; ties measure-zero for random normals):
//   region (1,1): cc=(ge==geh), tp=1 always  -> tp analytic = K^2
//   region (0,1) == region (1,0) transposed  -> compute once, double
//   region (0,0): contributes nothing        -> skipped entirely
// CC_full = Sum_A(ge==geh) + 2*Sum_B(ge&geh)
// TP_full = K^2           + 2*Sum_B(ge)
// Region A eq-count via XOR: eq = TJ - Sum(ge!=geh); j-pads (+inf,-inf)
// contribute exactly 1 to the XOR sum so the TJ constant absorbs them.
// i-pads (-inf,-inf): region A gated by (i<ilim); region B ge=false -> 0.
//
// Lesson from R3: hot loop MUST have compile-time trip count (TJ), uniform
// control flow, LDS float2 broadcast reads. Partition between kernels.

#define BLOCK 256
#define TI 256
#define TJ 512
#define GRID_MAIN 1024

// ws layout: [0] u32 cnt1, [4] u32 cnt0, [8..31] ull acc[3] (A, Bcc, Btp),
//            [64..] float y1[n], yh1[n], y0[n], yh0[n]

__global__ __launch_bounds__(256) void compact_kernel(
    const float* __restrict__ y, const float* __restrict__ yh,
    const int* __restrict__ status, int n,
    unsigned* __restrict__ cnts,
    float* __restrict__ y1, float* __restrict__ yh1,
    float* __restrict__ y0, float* __restrict__ yh0)
{
    int i = blockIdx.x * 256 + threadIdx.x;
    int lane = threadIdx.x & 63;
    bool act = i < n;
    float yv  = act ? y[i]  : 0.0f;
    float yhv = act ? yh[i] : 0.0f;
    bool st = act && (status[i] == 1);
    unsigned long long m1 = __ballot(st);
    unsigned long long m0 = __ballot(act && !st);
    unsigned long long lt = (lane == 63) ? ~0ull >> 1 : ((1ull << lane) - 1ull);
    unsigned b1 = 0, b0 = 0;
    if (lane == 0) {
        b1 = atomicAdd(&cnts[0], (unsigned)__popcll(m1));
        b0 = atomicAdd(&cnts[1], (unsigned)__popcll(m0));
    }
    b1 = __shfl(b1, 0, 64);
    b0 = __shfl(b0, 0, 64);
    if (st) {
        unsigned s = b1 + (unsigned)__popcll(m1 & lt);
        y1[s] = yv; yh1[s] = yhv;
    } else if (act) {
        unsigned s = b0 + (unsigned)__popcll(m0 & lt);
        y0[s] = yv; yh0[s] = yhv;
    }
}

__global__ __launch_bounds__(BLOCK) void pairs_kernel(
    const unsigned* __restrict__ cnts,
    const float* __restrict__ y1, const float* __restrict__ yh1,
    const float* __restrict__ y0, const float* __restrict__ yh0,
    unsigned long long* __restrict__ acc)
{
    __shared__ __align__(16) float2 s_yy[TJ];
    const int tid = threadIdx.x;
    const unsigned K = cnts[0], M = cnts[1];
    const int ntJ  = (int)((K + TJ - 1) / TJ);
    const int ntIA = (int)((K + TI - 1) / TI);
    const int ntIB = (int)((M + TI - 1) / TI);
    const int ntA  = ntIA * ntJ;
    const int ntot = ntA + ntIB * ntJ;

    const float PINF = __int_as_float(0x7f800000);
    const float NINF = __int_as_float(0xff800000);

    unsigned accA = 0, accBc = 0, accBt = 0;

    for (int t = blockIdx.x; t < ntot; t += gridDim.x) {
        bool isA = t < ntA;
        int tt = isA ? t : t - ntA;
        int ti = tt / ntJ;
        int tj = tt - ti * ntJ;
        int jbase = tj * TJ;
        int jcnt = (int)K - jbase; if (jcnt > TJ) jcnt = TJ;

        // stage j chunk (st=1 set), pads (+inf, -inf)
        for (int s = tid; s < TJ; s += BLOCK) {
            bool inb = s < jcnt;
            int j = jbase + s;
            float a = inb ? y1[j]  : PINF;
            float b = inb ? yh1[j] : NINF;
            s_yy[s] = make_float2(a, b);
        }
        __syncthreads();

        int i = ti * TI + tid;
        unsigned ilim = isA ? K : M;
        const float* py = isA ? y1  : y0;
        const float* ph = isA ? yh1 : yh0;
        bool iv = (unsigned)i < ilim;
        float yi  = iv ? py[i] : NINF;
        float yhi = iv ? ph[i] : NINF;

        if (isA) {
            unsigned ax = 0;
#pragma unroll 8
            for (int jj = 0; jj < TJ; ++jj) {
                float2 p = s_yy[jj];
                ax += (unsigned)((yi >= p.x) != (yhi >= p.y));
            }
            if (iv) accA += (unsigned)TJ - ax;   // eq-count, pads absorbed
        } else {
            unsigned bg = 0, bc = 0;
#pragma unroll 8
            for (int jj = 0; jj < TJ; ++jj) {
                float2 p = s_yy[jj];
                bool ge = yi >= p.x;
                bool gh = yhi >= p.y;
                bg += (unsigned)ge;
                bc += (unsigned)(ge & gh);
            }
            accBt += bg; accBc += bc;            // i-pads give 0 naturally
        }
        __syncthreads();
    }

    // reduce the three counters: wave shuffle -> LDS -> 3 atomics per block
#pragma unroll
    for (int off = 32; off > 0; off >>= 1) {
        accA  += __shfl_down(accA,  off, 64);
        accBc += __shfl_down(accBc, off, 64);
        accBt += __shfl_down(accBt, off, 64);
    }
    __shared__ unsigned rA[4], rC[4], rT[4];
    int wav = tid >> 6, lane = tid & 63;
    if (lane == 0) { rA[wav] = accA; rC[wav] = accBc; rT[wav] = accBt; }
    __syncthreads();
    if (tid == 0) {
        unsigned long long a = rA[0] + rA[1] + rA[2] + rA[3];
        unsigned long long c = rC[0] + rC[1] + rC[2] + rC[3];
        unsigned long long t = rT[0] + rT[1] + rT[2] + rT[3];
        if (a) atomicAdd(&acc[0], a);
        if (c) atomicAdd(&acc[1], c);
        if (t) atomicAdd(&acc[2], t);
    }
}

__global__ void finalize_kernel(const unsigned* __restrict__ cnts,
                                const unsigned long long* __restrict__ acc,
                                float* __restrict__ out)
{
    if (threadIdx.x == 0) {
        unsigned long long K = cnts[0];
        unsigned long long CC = acc[0] + 2ull * acc[1];
        unsigned long long TP = K * K + 2ull * acc[2];
        long long cn = (long long)CC - (long long)K;
        long long tn = (long long)TP - (long long)K;
        out[0] = (float)cn / (float)tn;
    }
}

extern "C" void kernel_launch(void* const* d_in, const int* in_sizes, int n_in,
                              void* d_out, int out_size, void* d_ws, size_t ws_size,
                              hipStream_t stream) {
    const float* y      = (const float*)d_in[0];
    const float* y_hat  = (const float*)d_in[1];
    const int*   status = (const int*)d_in[2];
    float* out = (float*)d_out;
    int n = in_sizes[0];

    char* base = (char*)d_ws;
    unsigned* cnts = (unsigned*)base;
    unsigned long long* acc = (unsigned long long*)(base + 8);
    float* y1  = (float*)(base + 64);
    float* yh1 = y1 + n;
    float* y0  = yh1 + n;
    float* yh0 = y0 + n;

    hipMemsetAsync(base, 0, 32, stream);

    hipLaunchKernelGGL(compact_kernel, dim3((n + 255) / 256), dim3(256), 0, stream,
                       y, y_hat, status, n, cnts, y1, yh1, y0, yh0);

    hipLaunchKernelGGL(pairs_kernel, dim3(GRID_MAIN), dim3(BLOCK), 0, stream,
                       cnts, y1, yh1, y0, yh0, acc);

    hipLaunchKernelGGL(finalize_kernel, dim3(1), dim3(64), 0, stream,
                       cnts, acc, out);
}